// Round 1
// baseline (260.977 us; speedup 1.0000x reference)
//
#include <hip/hip_runtime.h>
#include <math.h>

#define T_SAMPLES 16384
#define BC 128            // 64 batch * 2 channels
#define NUM_FREQS 257
#define NUM_TIMES 513

// Workspace layout (floats), spec stored as [bc][t][f] per resolution:
//  r0: N=64   F=33  NT=513  -> 128*513*33  = 2,166,912
//  r1: N=128  F=65  NT=257  -> 128*257*65  = 2,138,240
//  r2: N=256  F=129 NT=129  -> 128*129*129 = 2,130,048
//  r3: N=512  F=257 NT=65   -> 128*65*257  = 2,138,240
#define OFF0 0
#define OFF1 2166912
#define OFF2 4305152
#define OFF3 6435200
// total = 8,573,440 floats = 34.3 MB of d_ws

// Radix-2 DIT FFT per frame. HOP = N/2 threads cooperate on one frame;
// 512/N frames per 256-thread block. Input loaded bit-reversed with the
// Hann window and reflect padding fused into the load.
template <int LOGN>
__global__ __launch_bounds__(256) void fft_spec_kernel(const float* __restrict__ x,
                                                       float* __restrict__ spec) {
    constexpr int N   = 1 << LOGN;
    constexpr int HOP = N / 2;
    constexpr int F   = HOP + 1;
    constexpr int NT  = T_SAMPLES / HOP + 1;
    constexpr int FPB = 512 / N;   // frames per block (256 threads / HOP)

    __shared__ float2 data[FPB][N];
    __shared__ float2 twid[HOP];

    const int tid = threadIdx.x;
    const int j   = tid & (HOP - 1);        // butterfly lane within frame
    const int grp = tid >> (LOGN - 1);      // frame slot within block
    const int bc  = blockIdx.y;
    const int t   = blockIdx.x * FPB + grp; // frame index

    // Twiddle table: twid[i] = exp(-2*pi*i*i/N) = (cos, -sin)
    for (int i = tid; i < HOP; i += 256) {
        float s, c;
        sincosf(-2.0f * (float)M_PI * (float)i / (float)N, &s, &c);
        twid[i] = make_float2(c, s);
    }

    const bool active = (t < NT);
    if (active) {
        const float* xb = x + (size_t)bc * T_SAMPLES;
#pragma unroll
        for (int p = 0; p < 2; ++p) {
            int pos = j + p * HOP;
            int n   = __brev((unsigned)pos) >> (32 - LOGN);
            // global sample index with center pad (pad = HOP), reflect mode
            int g = t * HOP + n - HOP;
            g = (g < 0) ? -g : g;
            g = (g >= T_SAMPLES) ? (2 * T_SAMPLES - 2 - g) : g;
            float w = 0.5f - 0.5f * cosf((2.0f * (float)M_PI / (float)N) * (float)n);
            data[grp][pos] = make_float2(xb[g] * w, 0.0f);
        }
    }

    // log2(N) butterfly stages
    for (int s = 1; s <= LOGN; ++s) {
        __syncthreads();
        if (active) {
            const int half = 1 << (s - 1);
            const int k    = j & (half - 1);
            const int i1   = ((j >> (s - 1)) << s) + k;
            const int i2   = i1 + half;
            float2 tw = twid[k << (LOGN - s)];
            float2 u  = data[grp][i1];
            float2 v  = data[grp][i2];
            float2 tv = make_float2(v.x * tw.x - v.y * tw.y,
                                    v.x * tw.y + v.y * tw.x);
            data[grp][i1] = make_float2(u.x + tv.x, u.y + tv.y);
            data[grp][i2] = make_float2(u.x - tv.x, u.y - tv.y);
        }
    }
    __syncthreads();

    if (active) {
        const float norm = 8.0f / (3.0f * (float)N);  // 1 / sum(w^2), exact for periodic Hann
        float* srow = spec + ((size_t)bc * NT + t) * F;
        for (int f = j; f < F; f += HOP) {   // thread 0 also writes f = N/2
            float2 X = data[grp][f];
            srow[f] = (X.x * X.x + X.y * X.y) * norm;
        }
    }
}

__global__ __launch_bounds__(256) void remap_max_kernel(const float* __restrict__ ws,
                                                        float* __restrict__ out) {
    const int total = BC * NUM_FREQS * NUM_TIMES;
    int idx = blockIdx.x * 256 + threadIdx.x;
    if (idx >= total) return;
    int j   = idx % NUM_TIMES;
    int rem = idx / NUM_TIMES;
    int i   = rem % NUM_FREQS;
    int bc  = rem / NUM_FREQS;

    float m = 0.0f;
#define GATHER(OFF, F_, NT_)                                            \
    {                                                                   \
        int fi = (i * F_) / NUM_FREQS;                                  \
        int ti = (j * NT_) / NUM_TIMES;                                 \
        float v = ws[(size_t)(OFF) + ((size_t)bc * (NT_) + ti) * (F_) + fi]; \
        m = fmaxf(m, v);                                                \
    }
    GATHER(OFF0, 33, 513)
    GATHER(OFF1, 65, 257)
    GATHER(OFF2, 129, 129)
    GATHER(OFF3, 257, 65)
#undef GATHER
    out[idx] = m;
}

extern "C" void kernel_launch(void* const* d_in, const int* in_sizes, int n_in,
                              void* d_out, int out_size, void* d_ws, size_t ws_size,
                              hipStream_t stream) {
    const float* x = (const float*)d_in[0];
    float* ws  = (float*)d_ws;
    float* out = (float*)d_out;

    // NT per res: 513, 257, 129, 65; FPB per res: 8, 4, 2, 1 -> grid.x = 65 each
    fft_spec_kernel<6><<<dim3(65, BC), 256, 0, stream>>>(x, ws + OFF0);
    fft_spec_kernel<7><<<dim3(65, BC), 256, 0, stream>>>(x, ws + OFF1);
    fft_spec_kernel<8><<<dim3(65, BC), 256, 0, stream>>>(x, ws + OFF2);
    fft_spec_kernel<9><<<dim3(65, BC), 256, 0, stream>>>(x, ws + OFF3);

    const int total = BC * NUM_FREQS * NUM_TIMES;
    remap_max_kernel<<<(total + 255) / 256, 256, 0, stream>>>(ws, out);
}

// Round 2
// 214.421 us; speedup vs baseline: 1.2171x; 1.2171x over previous
//
#include <hip/hip_runtime.h>
#include <math.h>

#define T_SAMPLES 16384
#define BC 128            // 64 batch * 2 channels
#define NUM_FREQS 257
#define NUM_TIMES 513

// Workspace layout (floats), spec stored TRANSPOSED as [bc][f][t]:
//  r0: N=64   F=33  NT=513  -> 128*33*513  = 2,166,912
//  r1: N=128  F=65  NT=257  -> 128*65*257  = 2,138,240
//  r2: N=256  F=129 NT=129  -> 128*129*129 = 2,130,048
//  r3: N=512  F=257 NT=65   -> 128*257*65  = 2,138,240
#define OFF0 0
#define OFF1 2166912
#define OFF2 4305152
#define OFF3 6435200
// total = 8,573,440 floats = 34.3 MB of d_ws

// Radix-2 DIT FFT per frame; HOP=N/2 threads per frame, FPB=512/N frames
// in flight, looping to cover a TILE_T=16-frame tile. Power spectra land in
// an LDS tile [F][TILE_T] which is then written coalesced along t into the
// transposed [bc][f][t] layout (so the remap gather is coalesced).
template <int LOGN>
__global__ __launch_bounds__(256) void fft_spec_kernel(const float* __restrict__ x,
                                                       float* __restrict__ spec) {
    constexpr int N      = 1 << LOGN;
    constexpr int HOP    = N / 2;
    constexpr int F      = HOP + 1;
    constexpr int NT     = T_SAMPLES / HOP + 1;
    constexpr int FPB    = 512 / N;        // frames in flight per loop
    constexpr int TILE_T = 16;
    constexpr int LOOPS  = TILE_T / FPB;

    __shared__ float2 data[FPB][N];
    __shared__ float2 twid[HOP];
    __shared__ float  powtile[F][TILE_T + 1];   // +1 pad: conflict-free

    const int tid = threadIdx.x;
    const int j   = tid & (HOP - 1);        // butterfly lane within frame
    const int grp = tid >> (LOGN - 1);      // frame slot within block
    const int bc  = blockIdx.y;
    const int t0  = blockIdx.x * TILE_T;

    // Twiddles: twid[i] = (cos, -sin)(2*pi*i/N)
    for (int i = tid; i < HOP; i += 256) {
        float s, c;
        sincosf(-2.0f * (float)M_PI * (float)i / (float)N, &s, &c);
        twid[i] = make_float2(c, s);
    }
    __syncthreads();

    const float* xb   = x + (size_t)bc * T_SAMPLES;
    const float  norm = 8.0f / (3.0f * (float)N);  // 1/sum(w^2), periodic Hann

    for (int l = 0; l < LOOPS; ++l) {
        const int t      = t0 + l * FPB + grp;
        const int tl     = l * FPB + grp;
        const bool active = (t < NT);

        if (active) {
#pragma unroll
            for (int p = 0; p < 2; ++p) {
                int pos = j + p * HOP;
                int n   = __brev((unsigned)pos) >> (32 - LOGN);
                // center pad (= HOP) with reflect mode
                int g = t * HOP + n - HOP;
                g = (g < 0) ? -g : g;
                g = (g >= T_SAMPLES) ? (2 * T_SAMPLES - 2 - g) : g;
                // hann(n) = 0.5 - 0.5*cos(2*pi*n/N), via twiddle table
                float c = (n < HOP) ? twid[n].x : -twid[n - HOP].x;
                float w = 0.5f - 0.5f * c;
                data[grp][pos] = make_float2(xb[g] * w, 0.0f);
            }
        }

        // stages 1 .. LOGN-1 in LDS
        for (int s = 1; s <= LOGN - 1; ++s) {
            __syncthreads();
            if (active) {
                const int half = 1 << (s - 1);
                const int k    = j & (half - 1);
                const int i1   = ((j >> (s - 1)) << s) + k;
                const int i2   = i1 + half;
                float2 tw = twid[k << (LOGN - s)];
                float2 u  = data[grp][i1];
                float2 v  = data[grp][i2];
                float2 tv = make_float2(v.x * tw.x - v.y * tw.y,
                                        v.x * tw.y + v.y * tw.x);
                data[grp][i1] = make_float2(u.x + tv.x, u.y + tv.y);
                data[grp][i2] = make_float2(u.x - tv.x, u.y - tv.y);
            }
        }
        __syncthreads();

        // final stage peeled into registers: thread j owns bins j and j+HOP;
        // only bin HOP (j==0) of the upper half is needed (onesided).
        if (active) {
            float2 tw = twid[j];
            float2 u  = data[grp][j];
            float2 v  = data[grp][j + HOP];
            float2 tv = make_float2(v.x * tw.x - v.y * tw.y,
                                    v.x * tw.y + v.y * tw.x);
            float2 X1 = make_float2(u.x + tv.x, u.y + tv.y);
            powtile[j][tl] = (X1.x * X1.x + X1.y * X1.y) * norm;
            if (j == 0) {
                float2 X2 = make_float2(u.x - tv.x, u.y - tv.y);
                powtile[HOP][tl] = (X2.x * X2.x + X2.y * X2.y) * norm;
            }
        }
        __syncthreads();   // data[] reused next loop; powtile visible at end
    }

    // coalesced write: spec[bc][f][t0 .. t0+15], 64B runs along t
    float* sbase = spec + (size_t)bc * F * NT;
    for (int e = tid; e < F * TILE_T; e += 256) {
        int f  = e >> 4;          // TILE_T = 16
        int tl = e & 15;
        int t  = t0 + tl;
        if (t < NT) sbase[(size_t)f * NT + t] = powtile[f][tl];
    }
}

__global__ __launch_bounds__(256) void remap_max_kernel(const float* __restrict__ ws,
                                                        float* __restrict__ out) {
    const int total = BC * NUM_FREQS * NUM_TIMES;
    int idx = blockIdx.x * 256 + threadIdx.x;
    if (idx >= total) return;
    int j   = idx % NUM_TIMES;          // time   (fastest -> coalesced reads)
    int rem = idx / NUM_TIMES;
    int i   = rem % NUM_FREQS;          // freq
    int bc  = rem / NUM_FREQS;

    float m = 0.0f;
#define GATHER(OFF, F_, NT_)                                              \
    {                                                                     \
        int fi = (i * F_) / NUM_FREQS;                                    \
        int ti = (j * NT_) / NUM_TIMES;                                   \
        float v = ws[(size_t)(OFF) + ((size_t)bc * (F_) + fi) * (NT_) + ti]; \
        m = fmaxf(m, v);                                                  \
    }
    GATHER(OFF0, 33, 513)
    GATHER(OFF1, 65, 257)
    GATHER(OFF2, 129, 129)
    GATHER(OFF3, 257, 65)
#undef GATHER
    out[idx] = m;
}

extern "C" void kernel_launch(void* const* d_in, const int* in_sizes, int n_in,
                              void* d_out, int out_size, void* d_ws, size_t ws_size,
                              hipStream_t stream) {
    const float* x = (const float*)d_in[0];
    float* ws  = (float*)d_ws;
    float* out = (float*)d_out;

    // grid.x = ceil(NT / 16): 33, 17, 9, 5
    fft_spec_kernel<6><<<dim3(33, BC), 256, 0, stream>>>(x, ws + OFF0);
    fft_spec_kernel<7><<<dim3(17, BC), 256, 0, stream>>>(x, ws + OFF1);
    fft_spec_kernel<8><<<dim3(9,  BC), 256, 0, stream>>>(x, ws + OFF2);
    fft_spec_kernel<9><<<dim3(5,  BC), 256, 0, stream>>>(x, ws + OFF3);

    const int total = BC * NUM_FREQS * NUM_TIMES;
    remap_max_kernel<<<(total + 255) / 256, 256, 0, stream>>>(ws, out);
}

// Round 3
// 207.720 us; speedup vs baseline: 1.2564x; 1.0323x over previous
//
#include <hip/hip_runtime.h>
#include <math.h>

#define T_SAMPLES 16384
#define BC 128            // 64 batch * 2 channels
#define NUM_FREQS 257
#define NUM_TIMES 513

// Workspace layout (floats), spec stored TRANSPOSED as [bc][f][t]:
//  r0: N=64   F=33  NT=513   r1: N=128  F=65  NT=257
//  r2: N=256  F=129 NT=129   r3: N=512  F=257 NT=65
#define OFF0 0
#define OFF1 2166912
#define OFF2 4305152
#define OFF3 6435200
// total = 8,573,440 floats = 34.3 MB of d_ws

struct cplx { float x, y; };
__device__ inline cplx cmul(cplx a, cplx b) { return { a.x*b.x - a.y*b.y, a.x*b.y + a.y*b.x }; }
__device__ inline cplx cadd(cplx a, cplx b) { return { a.x+b.x, a.y+b.y }; }
__device__ inline cplx csub(cplx a, cplx b) { return { a.x-b.x, a.y-b.y }; }

// Shuffle-based DIF FFT: one wave per frame, R = N/64 complex points per lane,
// idx = r*64 + lane. Stages on register bits (b >= 6) are in-register; stages
// on lane bits (b = 5..0) use __shfl_xor. No barriers, no LDS in the FFT.
// Output lands bit-reversed; the bit-reversal is folded into the powtile
// scatter (f = brev(idx)). powtile column-swizzled to dodge bank conflicts.
template <int LOGN>
__device__ void fft_tile_body(const float* __restrict__ x, float* __restrict__ spec,
                              int tile, int bc, float* powtile) {
    constexpr int N    = 1 << LOGN;
    constexpr int HOP  = N / 2;
    constexpr int F    = HOP + 1;
    constexpr int NT   = T_SAMPLES / HOP + 1;
    constexpr int R    = N / 64;
    const float NORM   = 8.0f / (3.0f * (float)N);  // 1/sum(w^2), periodic Hann

    const int tid  = threadIdx.x;
    const int lane = tid & 63;
    const int wave = tid >> 6;
    const int t0   = tile * 16;

    // per-lane stage twiddles: tw[b] = exp(-2*pi*i * (lane mod 2^b) / 2^(b+1))
    cplx tw[LOGN];
#pragma unroll
    for (int b = 0; b < LOGN; ++b) {
        float k = (float)(lane & ((1 << b) - 1));
        float s, c;
        sincosf(-2.0f * (float)M_PI * k / (float)(1 << (b + 1)), &s, &c);
        tw[b] = { c, s };
    }

    // window weights (natural order n = r*64 + lane)
    float wr[R];
#pragma unroll
    for (int r = 0; r < R; ++r) {
        int n = r * 64 + lane;
        wr[r] = 0.5f - 0.5f * cosf(2.0f * (float)M_PI * (float)n / (float)N);
    }

    const float* xb = x + (size_t)bc * T_SAMPLES;

    for (int k4 = 0; k4 < 4; ++k4) {
        const int tl = 4 * k4 + wave;   // wave-uniform -> shuffles are safe
        const int t  = t0 + tl;
        if (t < NT) {
            cplx d[R];
            // coalesced windowed load with reflect padding (pad = HOP)
#pragma unroll
            for (int r = 0; r < R; ++r) {
                int n = r * 64 + lane;
                int g = t * HOP + n - HOP;
                g = (g < 0) ? -g : g;
                g = (g >= T_SAMPLES) ? (2 * T_SAMPLES - 2 - g) : g;
                d[r] = { xb[g] * wr[r], 0.0f };
            }

            // ---- in-register DIF stages (bits 8,7,6) ----
            if constexpr (LOGN >= 9) {   // b=8: pairs (r, r+4), tw8 * e^{-i*pi/4}^r
                const cplx u8 = { 0.70710678118654752f, -0.70710678118654752f };
                cplx tt = tw[8];
#pragma unroll
                for (int r = 0; r < 4; ++r) {
                    cplx a = d[r], b = d[r + 4];
                    d[r]     = cadd(a, b);
                    d[r + 4] = cmul(csub(a, b), tt);
                    tt = cmul(tt, u8);
                }
            }
            if constexpr (LOGN >= 8) {   // b=7: pairs (r, r+2); tw7, tw7*(-i)
                const cplx t0_ = tw[7];
                const cplx t1_ = { tw[7].y, -tw[7].x };
#pragma unroll
                for (int g = 0; g < R; g += 4) {
                    { cplx a = d[g],   b = d[g+2]; d[g]   = cadd(a,b); d[g+2] = cmul(csub(a,b), t0_); }
                    { cplx a = d[g+1], b = d[g+3]; d[g+1] = cadd(a,b); d[g+3] = cmul(csub(a,b), t1_); }
                }
            }
            if constexpr (LOGN >= 7) {   // b=6: pairs (r, r+1); tw6
#pragma unroll
                for (int g = 0; g < R; g += 2) {
                    cplx a = d[g], b = d[g+1];
                    d[g]   = cadd(a, b);
                    d[g+1] = cmul(csub(a, b), tw[6]);
                }
            }

            // ---- cross-lane DIF stages (bits 5..0) via shfl_xor ----
#pragma unroll
            for (int b = 5; b >= 0; --b) {
                const int  mask = 1 << b;
                const bool hi   = (lane & mask) != 0;
                const cplx twb  = tw[b];
#pragma unroll
                for (int r = 0; r < R; ++r) {
                    cplx p;
                    p.x = __shfl_xor(d[r].x, mask, 64);
                    p.y = __shfl_xor(d[r].y, mask, 64);
                    cplx u = { hi ? p.x : d[r].x, hi ? p.y : d[r].y };
                    cplx v = { hi ? d[r].x : p.x, hi ? d[r].y : p.y };
                    cplx s = cadd(u, v);
                    cplx q = csub(u, v);
                    if (b != 0) q = cmul(q, twb);
                    d[r].x = hi ? q.x : s.x;
                    d[r].y = hi ? q.y : s.y;
                }
            }

            // power spectrum -> swizzled powtile (bit-reversal folded in)
#pragma unroll
            for (int r = 0; r < R; ++r) {
                int idx = r * 64 + lane;
                int f   = (int)(__brev((unsigned)idx) >> (32 - LOGN));
                if (f <= HOP) {
                    float pw = (d[r].x * d[r].x + d[r].y * d[r].y) * NORM;
                    powtile[f * 16 + ((tl + (f >> 3)) & 15)] = pw;
                }
            }
        }
    }

    __syncthreads();
    // coalesced transposed write: spec[bc][f][t0..t0+15]
    float* sbase = spec + (size_t)bc * F * NT;
    for (int e = tid; e < F * 16; e += 256) {
        int f  = e >> 4;
        int tl = e & 15;
        int t  = t0 + tl;
        if (t < NT) sbase[(size_t)f * NT + t] = powtile[f * 16 + ((tl + (f >> 3)) & 15)];
    }
}

// One fused kernel for all four resolutions: blockIdx.x = tile id over
// [0,33) N=64 | [33,50) N=128 | [50,59) N=256 | [59,64) N=512.
__global__ __launch_bounds__(256) void fft_all_kernel(const float* __restrict__ x,
                                                      float* __restrict__ ws) {
    __shared__ float powtile[257 * 16];   // 16.4 KB, sized for max F
    const int bx = blockIdx.x;
    const int bc = blockIdx.y;
    if (bx < 33)       fft_tile_body<6>(x, ws + OFF0, bx,      bc, powtile);
    else if (bx < 50)  fft_tile_body<7>(x, ws + OFF1, bx - 33, bc, powtile);
    else if (bx < 59)  fft_tile_body<8>(x, ws + OFF2, bx - 50, bc, powtile);
    else               fft_tile_body<9>(x, ws + OFF3, bx - 59, bc, powtile);
}

__global__ __launch_bounds__(256) void remap_max_kernel(const float* __restrict__ ws,
                                                        float* __restrict__ out) {
    const int total = BC * NUM_FREQS * NUM_TIMES;
    int idx = blockIdx.x * 256 + threadIdx.x;
    if (idx >= total) return;
    int j   = idx % NUM_TIMES;          // time (fastest -> coalesced reads)
    int rem = idx / NUM_TIMES;
    int i   = rem % NUM_FREQS;          // freq
    int bc  = rem / NUM_FREQS;

    float m = 0.0f;
#define GATHER(OFF, F_, NT_)                                              \
    {                                                                     \
        int fi = (i * F_) / NUM_FREQS;                                    \
        int ti = (j * NT_) / NUM_TIMES;                                   \
        float v = ws[(size_t)(OFF) + ((size_t)bc * (F_) + fi) * (NT_) + ti]; \
        m = fmaxf(m, v);                                                  \
    }
    GATHER(OFF0, 33, 513)
    GATHER(OFF1, 65, 257)
    GATHER(OFF2, 129, 129)
    GATHER(OFF3, 257, 65)
#undef GATHER
    out[idx] = m;
}

extern "C" void kernel_launch(void* const* d_in, const int* in_sizes, int n_in,
                              void* d_out, int out_size, void* d_ws, size_t ws_size,
                              hipStream_t stream) {
    const float* x = (const float*)d_in[0];
    float* ws  = (float*)d_ws;
    float* out = (float*)d_out;

    fft_all_kernel<<<dim3(64, BC), 256, 0, stream>>>(x, ws);

    const int total = BC * NUM_FREQS * NUM_TIMES;
    remap_max_kernel<<<(total + 255) / 256, 256, 0, stream>>>(ws, out);
}

// Round 4
// 145.945 us; speedup vs baseline: 1.7882x; 1.4233x over previous
//
#include <hip/hip_runtime.h>
#include <math.h>

#define T_SAMPLES 16384
#define BC 128            // 64 batch * 2 channels
#define NUM_FREQS 257
#define NUM_TIMES 513

// Workspace layout (floats), spec stored TRANSPOSED as [bc][f][t]:
//  r0: N=64   F=33  NT=513   r1: N=128  F=65  NT=257
//  r2: N=256  F=129 NT=129   r3: N=512  F=257 NT=65
#define OFF0 0
#define OFF1 2166912
#define OFF2 4305152
#define OFF3 6435200

struct cplx { float x, y; };
__device__ inline cplx cmul(cplx a, cplx b) { return { a.x*b.x - a.y*b.y, a.x*b.y + a.y*b.x }; }
__device__ inline cplx cadd(cplx a, cplx b) { return { a.x+b.x, a.y+b.y }; }
__device__ inline cplx csub(cplx a, cplx b) { return { a.x-b.x, a.y-b.y }; }

// Packed-real shuffle FFT: one wave per PAIR of frames (z = x[2m] + i*x[2m+1]),
// R = N/64 complex regs/lane, idx = r*64 + lane, DIF (natural in, brev out).
// Register stages (bits >= 6) in-register; lane stages via shfl_xor with the
// sign-trick butterfly d = (p + s*d) * tw_eff  (tw_eff = hi ? tw : 1).
// Full Z scattered (bit-reversal resolved) into swizzled SoA LDS; Hermitian
// separation |X1|^2,|X2|^2 fused into the coalesced transposed write.
template <int LOGN, int P>
__device__ void fft_tile_body(const float* __restrict__ x, float* __restrict__ spec,
                              int tile, int bc, float* smem) {
    constexpr int N     = 1 << LOGN;
    constexpr int HOP   = N / 2;
    constexpr int F     = HOP + 1;
    constexpr int NT    = T_SAMPLES / HOP + 1;
    constexpr int NPAIR = (NT + 1) / 2;
    constexpr int R     = N / 64;
    constexpr int RS    = N + N / 32 + 2;   // swizzled row stride (floats)
    constexpr int W     = 2 * P;            // frames (t columns) per tile
    const float NORM    = 8.0f / (3.0f * (float)N);  // 1/sum(w^2), periodic Hann

    float* zre = smem;
    float* zim = smem + P * RS;

    const int tid   = threadIdx.x;
    const int lane  = tid & 63;
    const int wave  = tid >> 6;
    const int pair0 = tile * P;
    const int t0    = pair0 * 2;

    // lane-stage twiddles + sign trick constants
    float sgn[6];
    cplx  twe[6];
#pragma unroll
    for (int b = 0; b < 6; ++b) {
        const bool hi = (lane >> b) & 1;
        float k = (float)(lane & ((1 << b) - 1));
        float s, c;
        sincosf(-2.0f * (float)M_PI * k / (float)(1 << (b + 1)), &s, &c);
        twe[b] = hi ? cplx{c, s} : cplx{1.0f, 0.0f};
        sgn[b] = hi ? -1.0f : 1.0f;
    }
    cplx tw6 = {1,0}, tw7 = {1,0}, tw8 = {1,0};
    if constexpr (LOGN >= 7) { float s,c; sincosf(-2.0f*(float)M_PI*(float)lane/128.0f,&s,&c); tw6={c,s}; }
    if constexpr (LOGN >= 8) { float s,c; sincosf(-2.0f*(float)M_PI*(float)lane/256.0f,&s,&c); tw7={c,s}; }
    if constexpr (LOGN >= 9) { float s,c; sincosf(-2.0f*(float)M_PI*(float)lane/512.0f,&s,&c); tw8={c,s}; }

    float wr[R];
#pragma unroll
    for (int r = 0; r < R; ++r) {
        int n = r * 64 + lane;
        wr[r] = 0.5f - 0.5f * cosf(2.0f * (float)M_PI * (float)n / (float)N);
    }

    const float* xb = x + (size_t)bc * T_SAMPLES;

    constexpr int KLOOP = P / 4;    // pairs per wave
    for (int k2 = 0; k2 < KLOOP; ++k2) {
        const int p  = k2 * 4 + wave;     // local pair slot (wave-uniform)
        const int pg = pair0 + p;         // global pair
        if (pg < NPAIR) {
            const int t1 = 2 * pg, t2 = t1 + 1;
            cplx d[R];
            // windowed packed load, reflect pad (= HOP); frames overlap by HOP
#pragma unroll
            for (int r = 0; r < R; ++r) {
                int n = r * 64 + lane;
                int g = t1 * HOP + n - HOP;
                g = (g < 0) ? -g : g;
                g = (g >= T_SAMPLES) ? (2 * T_SAMPLES - 2 - g) : g;
                float re = xb[g] * wr[r];
                float im = 0.0f;
                if (t2 < NT) {
                    int h = t2 * HOP + n - HOP;
                    h = (h < 0) ? -h : h;
                    h = (h >= T_SAMPLES) ? (2 * T_SAMPLES - 2 - h) : h;
                    im = xb[h] * wr[r];
                }
                d[r] = { re, im };
            }

            // ---- in-register DIF stages (bits 8,7,6) ----
            if constexpr (LOGN >= 9) {   // pairs (r, r+4), tw = tw8 * e^{-i*pi/4}^r
                const cplx u8 = { 0.70710678118654752f, -0.70710678118654752f };
                cplx tt = tw8;
#pragma unroll
                for (int r = 0; r < 4; ++r) {
                    cplx a = d[r], b = d[r + 4];
                    d[r]     = cadd(a, b);
                    d[r + 4] = cmul(csub(a, b), tt);
                    tt = cmul(tt, u8);
                }
            }
            if constexpr (LOGN >= 8) {   // pairs (r, r+2); tw7, tw7*(-i)
                const cplx t0_ = tw7;
                const cplx t1_ = { tw7.y, -tw7.x };
#pragma unroll
                for (int g = 0; g < R; g += 4) {
                    { cplx a = d[g],   b = d[g+2]; d[g]   = cadd(a,b); d[g+2] = cmul(csub(a,b), t0_); }
                    { cplx a = d[g+1], b = d[g+3]; d[g+1] = cadd(a,b); d[g+3] = cmul(csub(a,b), t1_); }
                }
            }
            if constexpr (LOGN >= 7) {   // pairs (r, r+1); tw6
#pragma unroll
                for (int g = 0; g < R; g += 2) {
                    cplx a = d[g], b = d[g+1];
                    d[g]   = cadd(a, b);
                    d[g+1] = cmul(csub(a, b), tw6);
                }
            }

            // ---- cross-lane DIF stages (bits 5..1), sign-trick butterfly ----
#pragma unroll
            for (int b = 5; b >= 1; --b) {
                const int   mask = 1 << b;
                const cplx  w    = twe[b];
                const float s    = sgn[b];
#pragma unroll
                for (int r = 0; r < R; ++r) {
                    float px = __shfl_xor(d[r].x, mask, 64);
                    float py = __shfl_xor(d[r].y, mask, 64);
                    float tx = fmaf(s, d[r].x, px);
                    float ty = fmaf(s, d[r].y, py);
                    d[r].x = tx * w.x - ty * w.y;
                    d[r].y = tx * w.y + ty * w.x;
                }
            }
            {   // bit 0: twiddle == 1
                const float s = sgn[0];
#pragma unroll
                for (int r = 0; r < R; ++r) {
                    float px = __shfl_xor(d[r].x, 1, 64);
                    float py = __shfl_xor(d[r].y, 1, 64);
                    d[r].x = fmaf(s, d[r].x, px);
                    d[r].y = fmaf(s, d[r].y, py);
                }
            }

            // scatter full Z, bit-reversal resolved; swizzle keeps it ~2-way
#pragma unroll
            for (int r = 0; r < R; ++r) {
                int idx = r * 64 + lane;
                int f   = (int)(__brev((unsigned)idx) >> (32 - LOGN));
                int pos = p * RS + f + (f >> 5);
                zre[pos] = d[r].x;
                zim[pos] = d[r].y;
            }
        }
    }
    __syncthreads();

    // Hermitian separation + coalesced transposed write: spec[bc][f][t0..t0+W)
    float* sbase = spec + (size_t)bc * F * NT;
    for (int e = tid; e < F * W; e += 256) {
        int f  = e / W;        // W is a power of two -> shifts
        int tl = e % W;
        int t  = t0 + tl;
        if (t < NT) {
            int p  = tl >> 1;
            int fn = (N - f) & (N - 1);
            int pa = p * RS + f  + (f  >> 5);
            int pb = p * RS + fn + (fn >> 5);
            float ax = zre[pa], ay = zim[pa];
            float bx = zre[pb], by = zim[pb];
            float rx, ry;
            if (tl & 1) { rx = ax - bx; ry = ay + by; }   // X2 = (Z - conj(Zn))/2i
            else        { rx = ax + bx; ry = ay - by; }   // X1 = (Z + conj(Zn))/2
            sbase[(size_t)f * NT + t] = (rx * rx + ry * ry) * (0.25f * NORM);
        }
    }
}

// Fused kernel: blockIdx.x tiles: [0,33) N=64 | [33,50) N=128 | [50,59) N=256 | [59,68) N=512
__global__ __launch_bounds__(256) void fft_all_kernel(const float* __restrict__ x,
                                                      float* __restrict__ ws) {
    __shared__ float smem[4256];   // max over res of 2*P*RS floats (17 KB)
    const int bx = blockIdx.x;
    const int bc = blockIdx.y;
    if (bx < 33)       fft_tile_body<6, 8>(x, ws + OFF0, bx,      bc, smem);
    else if (bx < 50)  fft_tile_body<7, 8>(x, ws + OFF1, bx - 33, bc, smem);
    else if (bx < 59)  fft_tile_body<8, 8>(x, ws + OFF2, bx - 50, bc, smem);
    else               fft_tile_body<9, 4>(x, ws + OFF3, bx - 59, bc, smem);
}

__global__ __launch_bounds__(256) void remap_max_kernel(const float* __restrict__ ws,
                                                        float* __restrict__ out) {
    const int total = BC * NUM_FREQS * NUM_TIMES;
    int idx = blockIdx.x * 256 + threadIdx.x;
    if (idx >= total) return;
    int j   = idx % NUM_TIMES;          // time (fastest -> coalesced reads)
    int rem = idx / NUM_TIMES;
    int i   = rem % NUM_FREQS;          // freq
    int bc  = rem / NUM_FREQS;

    float m = 0.0f;
#define GATHER(OFF, F_, NT_)                                              \
    {                                                                     \
        int fi = (i * F_) / NUM_FREQS;                                    \
        int ti = (j * NT_) / NUM_TIMES;                                   \
        float v = ws[(size_t)(OFF) + ((size_t)bc * (F_) + fi) * (NT_) + ti]; \
        m = fmaxf(m, v);                                                  \
    }
    GATHER(OFF0, 33, 513)
    GATHER(OFF1, 65, 257)
    GATHER(OFF2, 129, 129)
    GATHER(OFF3, 257, 65)
#undef GATHER
    out[idx] = m;
}

extern "C" void kernel_launch(void* const* d_in, const int* in_sizes, int n_in,
                              void* d_out, int out_size, void* d_ws, size_t ws_size,
                              hipStream_t stream) {
    const float* x = (const float*)d_in[0];
    float* ws  = (float*)d_ws;
    float* out = (float*)d_out;

    fft_all_kernel<<<dim3(68, BC), 256, 0, stream>>>(x, ws);

    const int total = BC * NUM_FREQS * NUM_TIMES;
    remap_max_kernel<<<(total + 255) / 256, 256, 0, stream>>>(ws, out);
}

// Round 5
// 136.157 us; speedup vs baseline: 1.9167x; 1.0719x over previous
//
#include <hip/hip_runtime.h>
#include <math.h>

#define T_SAMPLES 16384
#define BC 128            // 64 batch * 2 channels
#define NUM_FREQS 257
#define NUM_TIMES 513

// Workspace layout (floats), spec stored TRANSPOSED as [bc][f][t]:
//  r0: N=64   F=33  NT=513   r1: N=128  F=65  NT=257
//  r2: N=256  F=129 NT=129   r3: N=512  F=257 NT=65
#define OFF0 0
#define OFF1 2166912
#define OFF2 4305152
#define OFF3 6435200

typedef float vf2 __attribute__((ext_vector_type(2)));
typedef float vf4 __attribute__((ext_vector_type(4)));
typedef vf4 vf4u __attribute__((aligned(4)));   // unaligned-capable float4

// complex helpers on packed float2: (a*b) = b.x*a + b.y*(-a.y, a.x)
__device__ inline vf2 cmul(vf2 a, vf2 b) {
    vf2 ar = { -a.y, a.x };
    return b.x * a + b.y * ar;
}

// Packed-real shuffle FFT: one wave per PAIR of frames (z = x[2m] + i*x[2m+1]),
// R = N/64 complex regs/lane, idx = r*64 + lane, DIF (natural in, brev out).
// Register stages (bits >= 6) in-register; lane stages via shfl_xor with the
// sign-trick butterfly t = p + s*d; d = tw_eff * t (tw_eff = hi ? tw : 1).
// Full Z scattered (bit-reversal resolved) into swizzled SoA LDS; Hermitian
// separation fused into the coalesced transposed write (X1,X2 per thread).
template <int LOGN, int P>
__device__ void fft_tile_body(const float* __restrict__ x, float* __restrict__ spec,
                              int tile, int bc, float* smem) {
    constexpr int N     = 1 << LOGN;
    constexpr int HOP   = N / 2;
    constexpr int F     = HOP + 1;
    constexpr int NT    = T_SAMPLES / HOP + 1;
    constexpr int NPAIR = (NT + 1) / 2;
    constexpr int R     = N / 64;
    constexpr int RS    = N + N / 32 + 2;   // swizzled row stride (floats)
    const float NORM4   = 0.25f * 8.0f / (3.0f * (float)N);  // 1/(4*sum(w^2))

    float* zre = smem;
    float* zim = smem + P * RS;

    const int tid   = threadIdx.x;
    const int lane  = tid & 63;
    const int wave  = tid >> 6;
    const int pair0 = tile * P;
    const int t0    = pair0 * 2;

    // lane-stage twiddles + sign-trick constants
    float sgn[6];
    vf2   twe[6];
#pragma unroll
    for (int b = 0; b < 6; ++b) {
        const bool hi = (lane >> b) & 1;
        float k = (float)(lane & ((1 << b) - 1));
        float s, c;
        sincosf(-2.0f * (float)M_PI * k / (float)(1 << (b + 1)), &s, &c);
        twe[b] = hi ? vf2{c, s} : vf2{1.0f, 0.0f};
        sgn[b] = hi ? -1.0f : 1.0f;
    }
    vf2 tw6 = {1,0}, tw7 = {1,0}, tw8 = {1,0};
    if constexpr (LOGN >= 7) { float s,c; sincosf(-2.0f*(float)M_PI*(float)lane/128.0f,&s,&c); tw6={c,s}; }
    if constexpr (LOGN >= 8) { float s,c; sincosf(-2.0f*(float)M_PI*(float)lane/256.0f,&s,&c); tw7={c,s}; }
    if constexpr (LOGN >= 9) { float s,c; sincosf(-2.0f*(float)M_PI*(float)lane/512.0f,&s,&c); tw8={c,s}; }

    float wr[R];
#pragma unroll
    for (int r = 0; r < R; ++r) {
        int n = r * 64 + lane;
        wr[r] = 0.5f - 0.5f * cosf(2.0f * (float)M_PI * (float)n / (float)N);
    }

    const float* xb = x + (size_t)bc * T_SAMPLES;

    constexpr int KLOOP = P / 4;    // pairs per wave
    for (int k2 = 0; k2 < KLOOP; ++k2) {
        const int p  = k2 * 4 + wave;     // local pair slot (wave-uniform)
        const int pg = pair0 + p;         // global pair
        if (pg < NPAIR) {
            const int t1 = 2 * pg, t2 = t1 + 1;
            vf2 d[R];

            // wave-uniform boundary test: reflection/short-frame only at edges
            const bool refl = (t1 == 0) || (t1 * HOP + N - 1 >= T_SAMPLES) || (t2 >= NT);
            if (!refl) {
                const float* src = xb + t1 * HOP - HOP;
#pragma unroll
                for (int r = 0; r < R; ++r) {
                    int n = r * 64 + lane;
                    vf2 v = { src[n], src[n + HOP] };   // frame t1 / t2 samples
                    d[r] = v * wr[r];
                }
            } else {
#pragma unroll
                for (int r = 0; r < R; ++r) {
                    int n = r * 64 + lane;
                    int g = t1 * HOP + n - HOP;
                    g = (g < 0) ? -g : g;
                    g = (g >= T_SAMPLES) ? (2 * T_SAMPLES - 2 - g) : g;
                    float re = xb[g] * wr[r];
                    float im = 0.0f;
                    if (t2 < NT) {
                        int h = t2 * HOP + n - HOP;
                        h = (h < 0) ? -h : h;
                        h = (h >= T_SAMPLES) ? (2 * T_SAMPLES - 2 - h) : h;
                        im = xb[h] * wr[r];
                    }
                    d[r] = { re, im };
                }
            }

            // ---- in-register DIF stages (bits 8,7,6) ----
            if constexpr (LOGN >= 9) {   // pairs (r, r+4), tw = tw8 * e^{-i*pi/4}^r
                const vf2 u8 = { 0.70710678118654752f, -0.70710678118654752f };
                vf2 tt = tw8;
#pragma unroll
                for (int r = 0; r < 4; ++r) {
                    vf2 a = d[r], b = d[r + 4];
                    d[r]     = a + b;
                    d[r + 4] = cmul(a - b, tt);
                    tt = cmul(tt, u8);
                }
            }
            if constexpr (LOGN >= 8) {   // pairs (r, r+2); tw7, tw7*(-i)
                const vf2 t0_ = tw7;
                const vf2 t1_ = { tw7.y, -tw7.x };
#pragma unroll
                for (int g = 0; g < R; g += 4) {
                    { vf2 a = d[g],   b = d[g+2]; d[g]   = a + b; d[g+2] = cmul(a - b, t0_); }
                    { vf2 a = d[g+1], b = d[g+3]; d[g+1] = a + b; d[g+3] = cmul(a - b, t1_); }
                }
            }
            if constexpr (LOGN >= 7) {   // pairs (r, r+1); tw6
#pragma unroll
                for (int g = 0; g < R; g += 2) {
                    vf2 a = d[g], b = d[g+1];
                    d[g]   = a + b;
                    d[g+1] = cmul(a - b, tw6);
                }
            }

            // ---- cross-lane DIF stages (bits 5..1), packed sign-trick ----
#pragma unroll
            for (int b = 5; b >= 1; --b) {
                const int   mask = 1 << b;
                const vf2   w    = twe[b];
                const float s    = sgn[b];
#pragma unroll
                for (int r = 0; r < R; ++r) {
                    vf2 p2;
                    p2.x = __shfl_xor(d[r].x, mask, 64);
                    p2.y = __shfl_xor(d[r].y, mask, 64);
                    vf2 t  = p2 + d[r] * s;
                    vf2 tr = { -t.y, t.x };
                    d[r] = w.x * t + w.y * tr;
                }
            }
            {   // bit 0: twiddle == 1
                const float s = sgn[0];
#pragma unroll
                for (int r = 0; r < R; ++r) {
                    vf2 p2;
                    p2.x = __shfl_xor(d[r].x, 1, 64);
                    p2.y = __shfl_xor(d[r].y, 1, 64);
                    d[r] = p2 + d[r] * s;
                }
            }

            // scatter full Z, bit-reversal resolved; swizzle keeps it ~2-way
#pragma unroll
            for (int r = 0; r < R; ++r) {
                int idx = r * 64 + lane;
                int f   = (int)(__brev((unsigned)idx) >> (32 - LOGN));
                int pos = p * RS + f + (f >> 5);
                zre[pos] = d[r].x;
                zim[pos] = d[r].y;
            }
        }
    }
    __syncthreads();

    // Hermitian separation: each thread produces X1 (t even) and X2 (t odd)
    // from one (Z[f], Z[N-f]) pair. Coalesced transposed write.
    float* sbase = spec + (size_t)bc * F * NT;
    for (int e = tid; e < F * P; e += 256) {
        int f = e / P;                     // P is a power of two
        int p = e % P;
        int t = t0 + 2 * p;
        if (t < NT) {
            int fn = (N - f) & (N - 1);
            int pa = p * RS + f  + (f  >> 5);
            int pb = p * RS + fn + (fn >> 5);
            float ax = zre[pa], ay = zim[pa];
            float bx = zre[pb], by = zim[pb];
            float rx = ax + bx, ry = ay - by;          // X1 = (Z + conj(Zn))/2
            sbase[(size_t)f * NT + t] = (rx * rx + ry * ry) * NORM4;
            if (t + 1 < NT) {
                float sx = ax - bx, sy = ay + by;      // X2 = (Z - conj(Zn))/2i
                sbase[(size_t)f * NT + t + 1] = (sx * sx + sy * sy) * NORM4;
            }
        }
    }
}

// Fused kernel: blockIdx.x tiles: [0,33) N=64 | [33,50) N=128 | [50,59) N=256 | [59,68) N=512
__global__ __launch_bounds__(256) void fft_all_kernel(const float* __restrict__ x,
                                                      float* __restrict__ ws) {
    __shared__ float smem[4256];   // max over res of 2*P*RS floats (17 KB)
    const int bx = blockIdx.x;
    const int bc = blockIdx.y;
    if (bx < 33)       fft_tile_body<6, 8>(x, ws + OFF0, bx,      bc, smem);
    else if (bx < 50)  fft_tile_body<7, 8>(x, ws + OFF1, bx - 33, bc, smem);
    else if (bx < 59)  fft_tile_body<8, 8>(x, ws + OFF2, bx - 50, bc, smem);
    else               fft_tile_body<9, 4>(x, ws + OFF3, bx - 59, bc, smem);
}

// 4 output columns (j) per thread; res-0 gather is an exact contiguous float4;
// float4 store (unaligned-capable).
__global__ __launch_bounds__(256) void remap_max_kernel(const float* __restrict__ ws,
                                                        float* __restrict__ out) {
    const int JG    = 129;                    // ceil(513/4)
    const int total = BC * NUM_FREQS * JG;
    int idx = blockIdx.x * 256 + threadIdx.x;
    if (idx >= total) return;
    int jg  = idx % JG;
    int rem = idx / JG;
    int i   = rem % NUM_FREQS;
    int bc  = rem / NUM_FREQS;
    int j0  = jg * 4;
    const bool full = (j0 + 3 < NUM_TIMES);

    float mv[4];
    {   // r0: NT_=513 -> ti == j exactly; contiguous float4
        int fi = (i * 33) / NUM_FREQS;
        const float* p = ws + OFF0 + ((size_t)bc * 33 + fi) * 513 + j0;
        if (full) {
            vf4 v = *(const vf4u*)p;
            mv[0] = v.x; mv[1] = v.y; mv[2] = v.z; mv[3] = v.w;
        } else {
            mv[0] = p[0]; mv[1] = mv[2] = mv[3] = 0.0f;
        }
    }
#pragma unroll
    for (int k = 0; k < 4; ++k) {
        int j = j0 + k;
        if (j < NUM_TIMES) {
#define GATHER(OFF, F_, NT_)                                                   \
            {                                                                  \
                int fi = (i * F_) / NUM_FREQS;                                 \
                int ti = (j * NT_) / NUM_TIMES;                                \
                float v = ws[(size_t)(OFF) + ((size_t)bc * (F_) + fi) * (NT_) + ti]; \
                mv[k] = fmaxf(mv[k], v);                                       \
            }
            GATHER(OFF1, 65, 257)
            GATHER(OFF2, 129, 129)
            GATHER(OFF3, 257, 65)
#undef GATHER
        }
    }

    float* po = out + ((size_t)bc * NUM_FREQS + i) * NUM_TIMES + j0;
    if (full) {
        vf4 v = { mv[0], mv[1], mv[2], mv[3] };
        *(vf4u*)po = v;
    } else {
        po[0] = mv[0];
    }
}

extern "C" void kernel_launch(void* const* d_in, const int* in_sizes, int n_in,
                              void* d_out, int out_size, void* d_ws, size_t ws_size,
                              hipStream_t stream) {
    const float* x = (const float*)d_in[0];
    float* ws  = (float*)d_ws;
    float* out = (float*)d_out;

    fft_all_kernel<<<dim3(68, BC), 256, 0, stream>>>(x, ws);

    const int total = BC * NUM_FREQS * 129;
    remap_max_kernel<<<(total + 255) / 256, 256, 0, stream>>>(ws, out);
}

// Round 6
// 128.929 us; speedup vs baseline: 2.0242x; 1.0561x over previous
//
#include <hip/hip_runtime.h>
#include <math.h>

#define T_SAMPLES 16384
#define BC 128            // 64 batch * 2 channels
#define NUM_FREQS 257
#define NUM_TIMES 513

// Workspace layout (floats), spec stored TRANSPOSED as [bc][f][t]:
//  r0: N=64   F=33  NT=513   r1: N=128  F=65  NT=257
//  r2: N=256  F=129 NT=129   r3: N=512  F=257 NT=65
#define OFF0 0
#define OFF1 2166912
#define OFF2 4305152
#define OFF3 6435200

typedef float vf2 __attribute__((ext_vector_type(2)));
typedef float vf4 __attribute__((ext_vector_type(4)));
typedef vf4 vf4u __attribute__((aligned(4)));   // unaligned-capable float4

// complex helpers on packed float2: (a*b) = b.x*a + b.y*(-a.y, a.x)
__device__ inline vf2 cmul(vf2 a, vf2 b) {
    vf2 ar = { -a.y, a.x };
    return b.x * a + b.y * ar;
}

// DPP lane exchange within quads (free quad_perm): 0xB1 = xor1, 0x4E = xor2
template <int CTRL>
__device__ inline float dppf(float x) {
    return __builtin_bit_cast(float,
        __builtin_amdgcn_update_dpp(0, __builtin_bit_cast(int, x),
                                    CTRL, 0xF, 0xF, true));
}

// Packed-real shuffle FFT, batched for ILP: one wave owns KLOOP = P/4 frame
// PAIRS (z = x[2m] + i*x[2m+1]) processed simultaneously (KLOOP*R == 8 for
// every resolution -> 8 independent butterfly chains per wave, latency
// hidden). DIF: register stages (bits >= 6) in-register; lane stages b=5..2
// via shfl_xor, b=1..0 via DPP quad_perm. Full Z scattered (bit-reversal
// resolved) into swizzled SoA LDS (odd row stride); Hermitian separation
// fused into the coalesced transposed write.
template <int LOGN, int P>
__device__ void fft_tile_body(const float* __restrict__ x, float* __restrict__ spec,
                              int tile, int bc, float* smem) {
    constexpr int N     = 1 << LOGN;
    constexpr int HOP   = N / 2;
    constexpr int F     = HOP + 1;
    constexpr int NT    = T_SAMPLES / HOP + 1;
    constexpr int NPAIR = (NT + 1) / 2;
    constexpr int R     = N / 64;
    constexpr int RS    = N + N / 32 + 1;   // ODD row stride: p*RS is a bank permutation
    constexpr int KLOOP = P / 4;            // pairs per wave (KLOOP*R == 8)
    const float NORM4   = 0.25f * 8.0f / (3.0f * (float)N);  // 1/(4*sum(w^2))

    float* zre = smem;
    float* zim = smem + P * RS;

    const int tid   = threadIdx.x;
    const int lane  = tid & 63;
    const int wave  = tid >> 6;
    const int pair0 = tile * P;
    const int t0    = pair0 * 2;

    // lane-stage twiddles + sign-trick constants
    float sgn[6];
    vf2   twe[6];
#pragma unroll
    for (int b = 0; b < 6; ++b) {
        const bool hi = (lane >> b) & 1;
        float k = (float)(lane & ((1 << b) - 1));
        float s, c;
        sincosf(-2.0f * (float)M_PI * k / (float)(1 << (b + 1)), &s, &c);
        twe[b] = hi ? vf2{c, s} : vf2{1.0f, 0.0f};
        sgn[b] = hi ? -1.0f : 1.0f;
    }
    vf2 tw6 = {1,0}, tw7 = {1,0}, tw8 = {1,0};
    if constexpr (LOGN >= 7) { float s,c; sincosf(-2.0f*(float)M_PI*(float)lane/128.0f,&s,&c); tw6={c,s}; }
    if constexpr (LOGN >= 8) { float s,c; sincosf(-2.0f*(float)M_PI*(float)lane/256.0f,&s,&c); tw7={c,s}; }
    if constexpr (LOGN >= 9) { float s,c; sincosf(-2.0f*(float)M_PI*(float)lane/512.0f,&s,&c); tw8={c,s}; }

    float wr[R];
#pragma unroll
    for (int r = 0; r < R; ++r) {
        int n = r * 64 + lane;
        wr[r] = 0.5f - 0.5f * cosf(2.0f * (float)M_PI * (float)n / (float)N);
    }

    const float* xb = x + (size_t)bc * T_SAMPLES;

    vf2  d[KLOOP][R];
    bool act[KLOOP];

    // ---- load ALL pairs up front (wave-uniform boundary tests) ----
#pragma unroll
    for (int q = 0; q < KLOOP; ++q) {
        const int p  = q * 4 + wave;
        const int pg = pair0 + p;
        act[q] = (pg < NPAIR);
        if (act[q]) {
            const int t1 = 2 * pg, t2 = t1 + 1;
            const bool refl = (t1 == 0) || (t1 * HOP + N - 1 >= T_SAMPLES) || (t2 >= NT);
            if (!refl) {
                const float* src = xb + t1 * HOP - HOP;
#pragma unroll
                for (int r = 0; r < R; ++r) {
                    int n = r * 64 + lane;
                    vf2 v = { src[n], src[n + HOP] };
                    d[q][r] = v * wr[r];
                }
            } else {
#pragma unroll
                for (int r = 0; r < R; ++r) {
                    int n = r * 64 + lane;
                    int g = t1 * HOP + n - HOP;
                    g = (g < 0) ? -g : g;
                    g = (g >= T_SAMPLES) ? (2 * T_SAMPLES - 2 - g) : g;
                    float re = xb[g] * wr[r];
                    float im = 0.0f;
                    if (t2 < NT) {
                        int h = t2 * HOP + n - HOP;
                        h = (h < 0) ? -h : h;
                        h = (h >= T_SAMPLES) ? (2 * T_SAMPLES - 2 - h) : h;
                        im = xb[h] * wr[r];
                    }
                    d[q][r] = { re, im };
                }
            }
        } else {
#pragma unroll
            for (int r = 0; r < R; ++r) d[q][r] = vf2{0.0f, 0.0f};
        }
    }

    // ---- in-register DIF stages (bits 8,7,6), all pairs ----
    if constexpr (LOGN >= 9) {
        const vf2 u8 = { 0.70710678118654752f, -0.70710678118654752f };
#pragma unroll
        for (int q = 0; q < KLOOP; ++q) {
            vf2 tt = tw8;
#pragma unroll
            for (int r = 0; r < 4; ++r) {
                vf2 a = d[q][r], b = d[q][r + 4];
                d[q][r]     = a + b;
                d[q][r + 4] = cmul(a - b, tt);
                tt = cmul(tt, u8);
            }
        }
    }
    if constexpr (LOGN >= 8) {
        const vf2 t0_ = tw7;
        const vf2 t1_ = { tw7.y, -tw7.x };
#pragma unroll
        for (int q = 0; q < KLOOP; ++q) {
#pragma unroll
            for (int g = 0; g < R; g += 4) {
                { vf2 a = d[q][g],   b = d[q][g+2]; d[q][g]   = a + b; d[q][g+2] = cmul(a - b, t0_); }
                { vf2 a = d[q][g+1], b = d[q][g+3]; d[q][g+1] = a + b; d[q][g+3] = cmul(a - b, t1_); }
            }
        }
    }
    if constexpr (LOGN >= 7) {
#pragma unroll
        for (int q = 0; q < KLOOP; ++q) {
#pragma unroll
            for (int g = 0; g < R; g += 2) {
                vf2 a = d[q][g], b = d[q][g+1];
                d[q][g]   = a + b;
                d[q][g+1] = cmul(a - b, tw6);
            }
        }
    }

    // ---- cross-lane stages b=5..2 (shfl_xor), 8 independent chains ----
#pragma unroll
    for (int b = 5; b >= 2; --b) {
        const int   mask = 1 << b;
        const vf2   w    = twe[b];
        const float s    = sgn[b];
#pragma unroll
        for (int q = 0; q < KLOOP; ++q) {
#pragma unroll
            for (int r = 0; r < R; ++r) {
                vf2 p2;
                p2.x = __shfl_xor(d[q][r].x, mask, 64);
                p2.y = __shfl_xor(d[q][r].y, mask, 64);
                vf2 t  = p2 + d[q][r] * s;
                vf2 tr = { -t.y, t.x };
                d[q][r] = w.x * t + w.y * tr;
            }
        }
    }
    // ---- b=1: DPP quad_perm [2,3,0,1] (xor 2) ----
    {
        const vf2   w = twe[1];
        const float s = sgn[1];
#pragma unroll
        for (int q = 0; q < KLOOP; ++q) {
#pragma unroll
            for (int r = 0; r < R; ++r) {
                vf2 p2 = { dppf<0x4E>(d[q][r].x), dppf<0x4E>(d[q][r].y) };
                vf2 t  = p2 + d[q][r] * s;
                vf2 tr = { -t.y, t.x };
                d[q][r] = w.x * t + w.y * tr;
            }
        }
    }
    // ---- b=0: DPP quad_perm [1,0,3,2] (xor 1), twiddle == 1 ----
    {
        const float s = sgn[0];
#pragma unroll
        for (int q = 0; q < KLOOP; ++q) {
#pragma unroll
            for (int r = 0; r < R; ++r) {
                vf2 p2 = { dppf<0xB1>(d[q][r].x), dppf<0xB1>(d[q][r].y) };
                d[q][r] = p2 + d[q][r] * s;
            }
        }
    }

    // ---- scatter full Z, bit-reversal resolved; (f>>5) swizzle: <=2-way ----
#pragma unroll
    for (int q = 0; q < KLOOP; ++q) {
        if (act[q]) {
            const int p = q * 4 + wave;
#pragma unroll
            for (int r = 0; r < R; ++r) {
                int idx = r * 64 + lane;
                int f   = (int)(__brev((unsigned)idx) >> (32 - LOGN));
                int pos = p * RS + f + (f >> 5);
                zre[pos] = d[q][r].x;
                zim[pos] = d[q][r].y;
            }
        }
    }
    __syncthreads();

    // Hermitian separation: X1 (t even) and X2 (t odd) from one (Z[f],Z[N-f])
    // pair. p fastest -> odd RS makes the LDS reads a bank permutation.
    float* sbase = spec + (size_t)bc * F * NT;
    for (int e = tid; e < F * P; e += 256) {
        int f = e / P;                     // P is a power of two
        int p = e % P;
        int t = t0 + 2 * p;
        if (t < NT) {
            int fn = (N - f) & (N - 1);
            int pa = p * RS + f  + (f  >> 5);
            int pb = p * RS + fn + (fn >> 5);
            float ax = zre[pa], ay = zim[pa];
            float bx = zre[pb], by = zim[pb];
            float rx = ax + bx, ry = ay - by;          // X1 = (Z + conj(Zn))/2
            sbase[(size_t)f * NT + t] = (rx * rx + ry * ry) * NORM4;
            if (t + 1 < NT) {
                float sx = ax - bx, sy = ay + by;      // X2 = (Z - conj(Zn))/2i
                sbase[(size_t)f * NT + t + 1] = (sx * sx + sy * sy) * NORM4;
            }
        }
    }
}

// Fused kernel, uniform 9 tiles per resolution:
// bx in [0,9) N=64 | [9,18) N=128 | [18,27) N=256 | [27,36) N=512
__global__ __launch_bounds__(256) void fft_all_kernel(const float* __restrict__ x,
                                                      float* __restrict__ ws) {
    __shared__ float smem[4288];   // max 2*P*RS floats = 17152 B (res0)
    const int bx = blockIdx.x;
    const int bc = blockIdx.y;
    if (bx < 9)        fft_tile_body<6, 32>(x, ws + OFF0, bx,      bc, smem);
    else if (bx < 18)  fft_tile_body<7, 16>(x, ws + OFF1, bx - 9,  bc, smem);
    else if (bx < 27)  fft_tile_body<8, 8> (x, ws + OFF2, bx - 18, bc, smem);
    else               fft_tile_body<9, 4> (x, ws + OFF3, bx - 27, bc, smem);
}

// 4 output columns (j) per thread; res-0 gather is an exact contiguous float4;
// float4 store (unaligned-capable).
__global__ __launch_bounds__(256) void remap_max_kernel(const float* __restrict__ ws,
                                                        float* __restrict__ out) {
    const int JG    = 129;                    // ceil(513/4)
    const int total = BC * NUM_FREQS * JG;
    int idx = blockIdx.x * 256 + threadIdx.x;
    if (idx >= total) return;
    int jg  = idx % JG;
    int rem = idx / JG;
    int i   = rem % NUM_FREQS;
    int bc  = rem / NUM_FREQS;
    int j0  = jg * 4;
    const bool full = (j0 + 3 < NUM_TIMES);

    float mv[4];
    {   // r0: NT_=513 -> ti == j exactly; contiguous float4
        int fi = (i * 33) / NUM_FREQS;
        const float* p = ws + OFF0 + ((size_t)bc * 33 + fi) * 513 + j0;
        if (full) {
            vf4 v = *(const vf4u*)p;
            mv[0] = v.x; mv[1] = v.y; mv[2] = v.z; mv[3] = v.w;
        } else {
            mv[0] = p[0]; mv[1] = mv[2] = mv[3] = 0.0f;
        }
    }
#pragma unroll
    for (int k = 0; k < 4; ++k) {
        int j = j0 + k;
        if (j < NUM_TIMES) {
#define GATHER(OFF, F_, NT_)                                                   \
            {                                                                  \
                int fi = (i * F_) / NUM_FREQS;                                 \
                int ti = (j * NT_) / NUM_TIMES;                                \
                float v = ws[(size_t)(OFF) + ((size_t)bc * (F_) + fi) * (NT_) + ti]; \
                mv[k] = fmaxf(mv[k], v);                                       \
            }
            GATHER(OFF1, 65, 257)
            GATHER(OFF2, 129, 129)
            GATHER(OFF3, 257, 65)
#undef GATHER
        }
    }

    float* po = out + ((size_t)bc * NUM_FREQS + i) * NUM_TIMES + j0;
    if (full) {
        vf4 v = { mv[0], mv[1], mv[2], mv[3] };
        *(vf4u*)po = v;
    } else {
        po[0] = mv[0];
    }
}

extern "C" void kernel_launch(void* const* d_in, const int* in_sizes, int n_in,
                              void* d_out, int out_size, void* d_ws, size_t ws_size,
                              hipStream_t stream) {
    const float* x = (const float*)d_in[0];
    float* ws  = (float*)d_ws;
    float* out = (float*)d_out;

    fft_all_kernel<<<dim3(36, BC), 256, 0, stream>>>(x, ws);

    const int total = BC * NUM_FREQS * 129;
    remap_max_kernel<<<(total + 255) / 256, 256, 0, stream>>>(ws, out);
}

// Round 7
// 124.189 us; speedup vs baseline: 2.1015x; 1.0382x over previous
//
#include <hip/hip_runtime.h>
#include <math.h>

#define T_SAMPLES 16384
#define BC 128            // 64 batch * 2 channels
#define NUM_FREQS 257
#define NUM_TIMES 513

// Workspace layout (floats), spec stored TRANSPOSED as [bc][f][t]:
//  r0: N=64   F=33  NT=513   r1: N=128  F=65  NT=257
//  r2: N=256  F=129 NT=129   r3: N=512  F=257 NT=65
#define OFF0 0
#define OFF1 2166912
#define OFF2 4305152
#define OFF3 6435200

typedef float vf2 __attribute__((ext_vector_type(2)));
typedef float vf4 __attribute__((ext_vector_type(4)));
typedef vf4 vf4u __attribute__((aligned(4)));   // unaligned-capable float4

// ---------- compile-time trig tables (no runtime sincosf) ----------
constexpr double CPI = 3.14159265358979323846;
constexpr double ctsin(double x) {
    double x2 = x * x, t = x, s = x;
    for (int n = 1; n <= 12; ++n) { t *= -x2 / (double)((2*n) * (2*n + 1)); s += t; }
    return s;
}
constexpr double ctcos(double x) {
    double x2 = x * x, t = 1.0, s = 1.0;
    for (int n = 1; n <= 12; ++n) { t *= -x2 / (double)((2*n - 1) * (2*n)); s += t; }
    return s;
}
struct Tables {
    float twe[6][64][2];   // stage twiddle, hi-folding baked in (lo lanes = 1)
    float twL[3][64][2];   // tw6 / tw7 / tw8 per lane
    float win[4][512];     // periodic Hann per resolution (N = 64<<r)
};
constexpr Tables make_tables() {
    Tables T{};
    for (int b = 0; b < 6; ++b)
        for (int l = 0; l < 64; ++l) {
            const bool hi = (l >> b) & 1;
            const int  k  = l & ((1 << b) - 1);
            const double a = -2.0 * CPI * (double)k / (double)(1 << (b + 1)); // |a| < pi
            T.twe[b][l][0] = hi ? (float)ctcos(a) : 1.0f;
            T.twe[b][l][1] = hi ? (float)ctsin(a) : 0.0f;
        }
    for (int i = 0; i < 3; ++i)
        for (int l = 0; l < 64; ++l) {
            const double a = -2.0 * CPI * (double)l / (double)(128 << i);     // |a| < pi
            T.twL[i][l][0] = (float)ctcos(a);
            T.twL[i][l][1] = (float)ctsin(a);
        }
    for (int r = 0; r < 4; ++r) {
        const int N = 64 << r;
        for (int n = 0; n < N; ++n) {
            const int m = (2 * n <= N) ? n : n - N;                            // |angle| <= pi
            const double a = 2.0 * CPI * (double)m / (double)N;
            T.win[r][n] = (float)(0.5 - 0.5 * ctcos(a));
        }
    }
    return T;
}
__device__ __constant__ Tables g_tab = make_tables();
// -------------------------------------------------------------------

// complex helpers on packed float2: (a*b) = b.x*a + b.y*(-a.y, a.x)
__device__ inline vf2 cmul(vf2 a, vf2 b) {
    vf2 ar = { -a.y, a.x };
    return b.x * a + b.y * ar;
}

// DPP lane exchange within quads (free quad_perm): 0xB1 = xor1, 0x4E = xor2
template <int CTRL>
__device__ inline float dppf(float x) {
    return __builtin_bit_cast(float,
        __builtin_amdgcn_update_dpp(0, __builtin_bit_cast(int, x),
                                    CTRL, 0xF, 0xF, true));
}

// Packed-real shuffle FFT, batched for ILP: one wave owns KLOOP = P/4 frame
// PAIRS (z = x[2m] + i*x[2m+1]) processed simultaneously (KLOOP*R == 8 for
// every resolution -> 8 independent butterfly chains per wave). DIF: register
// stages (bits >= 6) in-register; lane stages b=5..2 via shfl_xor, b=1..0 via
// DPP quad_perm. All twiddles/window from compile-time constant tables.
// Full Z scattered (bit-reversal resolved) into swizzled SoA LDS (odd row
// stride); Hermitian separation fused into the coalesced transposed write.
template <int LOGN, int P>
__device__ void fft_tile_body(const float* __restrict__ x, float* __restrict__ spec,
                              int tile, int bc, float* smem) {
    constexpr int N     = 1 << LOGN;
    constexpr int HOP   = N / 2;
    constexpr int F     = HOP + 1;
    constexpr int NT    = T_SAMPLES / HOP + 1;
    constexpr int NPAIR = (NT + 1) / 2;
    constexpr int R     = N / 64;
    constexpr int RS    = N + N / 32 + 1;   // ODD row stride: p*RS is a bank permutation
    constexpr int KLOOP = P / 4;            // pairs per wave (KLOOP*R == 8)
    const float NORM4   = 0.25f * 8.0f / (3.0f * (float)N);  // 1/(4*sum(w^2))

    float* zre = smem;
    float* zim = smem + P * RS;

    const int tid   = threadIdx.x;
    const int lane  = tid & 63;
    const int wave  = tid >> 6;
    const int pair0 = tile * P;
    const int t0    = pair0 * 2;

    // table loads replace all runtime trig
    float sgn[6];
    vf2   twe[6];
#pragma unroll
    for (int b = 0; b < 6; ++b) {
        twe[b] = *(const vf2*)g_tab.twe[b][lane];
        sgn[b] = ((lane >> b) & 1) ? -1.0f : 1.0f;
    }
    vf2 tw6 = {1,0}, tw7 = {1,0}, tw8 = {1,0};
    if constexpr (LOGN >= 7) tw6 = *(const vf2*)g_tab.twL[0][lane];
    if constexpr (LOGN >= 8) tw7 = *(const vf2*)g_tab.twL[1][lane];
    if constexpr (LOGN >= 9) tw8 = *(const vf2*)g_tab.twL[2][lane];

    float wr[R];
#pragma unroll
    for (int r = 0; r < R; ++r) wr[r] = g_tab.win[LOGN - 6][r * 64 + lane];

    const float* xb = x + (size_t)bc * T_SAMPLES;

    vf2  d[KLOOP][R];
    bool act[KLOOP];

    // ---- load ALL pairs up front (wave-uniform boundary tests) ----
#pragma unroll
    for (int q = 0; q < KLOOP; ++q) {
        const int p  = q * 4 + wave;
        const int pg = pair0 + p;
        act[q] = (pg < NPAIR);
        if (act[q]) {
            const int t1 = 2 * pg, t2 = t1 + 1;
            const bool refl = (t1 == 0) || (t1 * HOP + N - 1 >= T_SAMPLES) || (t2 >= NT);
            if (!refl) {
                const float* src = xb + t1 * HOP - HOP;
#pragma unroll
                for (int r = 0; r < R; ++r) {
                    int n = r * 64 + lane;
                    vf2 v = { src[n], src[n + HOP] };
                    d[q][r] = v * wr[r];
                }
            } else {
#pragma unroll
                for (int r = 0; r < R; ++r) {
                    int n = r * 64 + lane;
                    int g = t1 * HOP + n - HOP;
                    g = (g < 0) ? -g : g;
                    g = (g >= T_SAMPLES) ? (2 * T_SAMPLES - 2 - g) : g;
                    float re = xb[g] * wr[r];
                    float im = 0.0f;
                    if (t2 < NT) {
                        int h = t2 * HOP + n - HOP;
                        h = (h < 0) ? -h : h;
                        h = (h >= T_SAMPLES) ? (2 * T_SAMPLES - 2 - h) : h;
                        im = xb[h] * wr[r];
                    }
                    d[q][r] = { re, im };
                }
            }
        } else {
#pragma unroll
            for (int r = 0; r < R; ++r) d[q][r] = vf2{0.0f, 0.0f};
        }
    }

    // ---- in-register DIF stages (bits 8,7,6), all pairs ----
    if constexpr (LOGN >= 9) {
        const vf2 u8 = { 0.70710678118654752f, -0.70710678118654752f };
#pragma unroll
        for (int q = 0; q < KLOOP; ++q) {
            vf2 tt = tw8;
#pragma unroll
            for (int r = 0; r < 4; ++r) {
                vf2 a = d[q][r], b = d[q][r + 4];
                d[q][r]     = a + b;
                d[q][r + 4] = cmul(a - b, tt);
                tt = cmul(tt, u8);
            }
        }
    }
    if constexpr (LOGN >= 8) {
        const vf2 t0_ = tw7;
        const vf2 t1_ = { tw7.y, -tw7.x };
#pragma unroll
        for (int q = 0; q < KLOOP; ++q) {
#pragma unroll
            for (int g = 0; g < R; g += 4) {
                { vf2 a = d[q][g],   b = d[q][g+2]; d[q][g]   = a + b; d[q][g+2] = cmul(a - b, t0_); }
                { vf2 a = d[q][g+1], b = d[q][g+3]; d[q][g+1] = a + b; d[q][g+3] = cmul(a - b, t1_); }
            }
        }
    }
    if constexpr (LOGN >= 7) {
#pragma unroll
        for (int q = 0; q < KLOOP; ++q) {
#pragma unroll
            for (int g = 0; g < R; g += 2) {
                vf2 a = d[q][g], b = d[q][g+1];
                d[q][g]   = a + b;
                d[q][g+1] = cmul(a - b, tw6);
            }
        }
    }

    // ---- cross-lane stages b=5..2 (shfl_xor), 8 independent chains ----
#pragma unroll
    for (int b = 5; b >= 2; --b) {
        const int   mask = 1 << b;
        const vf2   w    = twe[b];
        const float s    = sgn[b];
#pragma unroll
        for (int q = 0; q < KLOOP; ++q) {
#pragma unroll
            for (int r = 0; r < R; ++r) {
                vf2 p2;
                p2.x = __shfl_xor(d[q][r].x, mask, 64);
                p2.y = __shfl_xor(d[q][r].y, mask, 64);
                vf2 t  = p2 + d[q][r] * s;
                vf2 tr = { -t.y, t.x };
                d[q][r] = w.x * t + w.y * tr;
            }
        }
    }
    // ---- b=1: DPP quad_perm [2,3,0,1] (xor 2) ----
    {
        const vf2   w = twe[1];
        const float s = sgn[1];
#pragma unroll
        for (int q = 0; q < KLOOP; ++q) {
#pragma unroll
            for (int r = 0; r < R; ++r) {
                vf2 p2 = { dppf<0x4E>(d[q][r].x), dppf<0x4E>(d[q][r].y) };
                vf2 t  = p2 + d[q][r] * s;
                vf2 tr = { -t.y, t.x };
                d[q][r] = w.x * t + w.y * tr;
            }
        }
    }
    // ---- b=0: DPP quad_perm [1,0,3,2] (xor 1), twiddle == 1 ----
    {
        const float s = sgn[0];
#pragma unroll
        for (int q = 0; q < KLOOP; ++q) {
#pragma unroll
            for (int r = 0; r < R; ++r) {
                vf2 p2 = { dppf<0xB1>(d[q][r].x), dppf<0xB1>(d[q][r].y) };
                d[q][r] = p2 + d[q][r] * s;
            }
        }
    }

    // ---- scatter full Z, bit-reversal resolved; (f>>5) swizzle: <=2-way ----
#pragma unroll
    for (int q = 0; q < KLOOP; ++q) {
        if (act[q]) {
            const int p = q * 4 + wave;
#pragma unroll
            for (int r = 0; r < R; ++r) {
                int idx = r * 64 + lane;
                int f   = (int)(__brev((unsigned)idx) >> (32 - LOGN));
                int pos = p * RS + f + (f >> 5);
                zre[pos] = d[q][r].x;
                zim[pos] = d[q][r].y;
            }
        }
    }
    __syncthreads();

    // Hermitian separation: X1 (t even) and X2 (t odd) from one (Z[f],Z[N-f])
    // pair. p fastest -> odd RS makes the LDS reads a bank permutation.
    float* sbase = spec + (size_t)bc * F * NT;
    for (int e = tid; e < F * P; e += 256) {
        int f = e / P;                     // P is a power of two
        int p = e % P;
        int t = t0 + 2 * p;
        if (t < NT) {
            int fn = (N - f) & (N - 1);
            int pa = p * RS + f  + (f  >> 5);
            int pb = p * RS + fn + (fn >> 5);
            float ax = zre[pa], ay = zim[pa];
            float bx = zre[pb], by = zim[pb];
            float rx = ax + bx, ry = ay - by;          // X1 = (Z + conj(Zn))/2
            sbase[(size_t)f * NT + t] = (rx * rx + ry * ry) * NORM4;
            if (t + 1 < NT) {
                float sx = ax - bx, sy = ay + by;      // X2 = (Z - conj(Zn))/2i
                sbase[(size_t)f * NT + t + 1] = (sx * sx + sy * sy) * NORM4;
            }
        }
    }
}

// Fused kernel, uniform 9 tiles per resolution:
// bx in [0,9) N=64 | [9,18) N=128 | [18,27) N=256 | [27,36) N=512
__global__ __launch_bounds__(256) void fft_all_kernel(const float* __restrict__ x,
                                                      float* __restrict__ ws) {
    __shared__ float smem[4288];   // max 2*P*RS floats = 17152 B (res0)
    const int bx = blockIdx.x;
    const int bc = blockIdx.y;
    if (bx < 9)        fft_tile_body<6, 32>(x, ws + OFF0, bx,      bc, smem);
    else if (bx < 18)  fft_tile_body<7, 16>(x, ws + OFF1, bx - 9,  bc, smem);
    else if (bx < 27)  fft_tile_body<8, 8> (x, ws + OFF2, bx - 18, bc, smem);
    else               fft_tile_body<9, 4> (x, ws + OFF3, bx - 27, bc, smem);
}

// 4 output columns (j) per thread; res-0 gather is an exact contiguous float4;
// float4 store (unaligned-capable).
__global__ __launch_bounds__(256) void remap_max_kernel(const float* __restrict__ ws,
                                                        float* __restrict__ out) {
    const int JG    = 129;                    // ceil(513/4)
    const int total = BC * NUM_FREQS * JG;
    int idx = blockIdx.x * 256 + threadIdx.x;
    if (idx >= total) return;
    int jg  = idx % JG;
    int rem = idx / JG;
    int i   = rem % NUM_FREQS;
    int bc  = rem / NUM_FREQS;
    int j0  = jg * 4;
    const bool full = (j0 + 3 < NUM_TIMES);

    float mv[4];
    {   // r0: NT_=513 -> ti == j exactly; contiguous float4
        int fi = (i * 33) / NUM_FREQS;
        const float* p = ws + OFF0 + ((size_t)bc * 33 + fi) * 513 + j0;
        if (full) {
            vf4 v = *(const vf4u*)p;
            mv[0] = v.x; mv[1] = v.y; mv[2] = v.z; mv[3] = v.w;
        } else {
            mv[0] = p[0]; mv[1] = mv[2] = mv[3] = 0.0f;
        }
    }
#pragma unroll
    for (int k = 0; k < 4; ++k) {
        int j = j0 + k;
        if (j < NUM_TIMES) {
#define GATHER(OFF, F_, NT_)                                                   \
            {                                                                  \
                int fi = (i * F_) / NUM_FREQS;                                 \
                int ti = (j * NT_) / NUM_TIMES;                                \
                float v = ws[(size_t)(OFF) + ((size_t)bc * (F_) + fi) * (NT_) + ti]; \
                mv[k] = fmaxf(mv[k], v);                                       \
            }
            GATHER(OFF1, 65, 257)
            GATHER(OFF2, 129, 129)
            GATHER(OFF3, 257, 65)
#undef GATHER
        }
    }

    float* po = out + ((size_t)bc * NUM_FREQS + i) * NUM_TIMES + j0;
    if (full) {
        vf4 v = { mv[0], mv[1], mv[2], mv[3] };
        *(vf4u*)po = v;
    } else {
        po[0] = mv[0];
    }
}

extern "C" void kernel_launch(void* const* d_in, const int* in_sizes, int n_in,
                              void* d_out, int out_size, void* d_ws, size_t ws_size,
                              hipStream_t stream) {
    const float* x = (const float*)d_in[0];
    float* ws  = (float*)d_ws;
    float* out = (float*)d_out;

    fft_all_kernel<<<dim3(36, BC), 256, 0, stream>>>(x, ws);

    const int total = BC * NUM_FREQS * 129;
    remap_max_kernel<<<(total + 255) / 256, 256, 0, stream>>>(ws, out);
}